// Round 9
// baseline (287.360 us; speedup 1.0000x reference)
//
#include <hip/hip_runtime.h>
#include <hip/hip_fp16.h>

#define N_NODES 50000
#define N_EDGES 800000
#define DIM 128
#define LAYERS 4
#define SLOT 48           // padded slots per node; 4B/slot -> node region = 192B = 3 lines
#define EPB 8             // edges scanned per thread in bucket (N_EDGES % EPB == 0)

#define BUCKET_BLOCKS 3128   // ceil(800000/(256*8)) * 8 = 391*8
#define WT_BLOCKS 256        // LAYERS*DIM*DIM/256
#define INIT_BLOCKS 3125     // N_NODES*DIM/8/256 (8 elems -> 8 fp8 bytes per thread)

#define GTILES 1563          // ceil(50000/32) node-tiles per half
#define G_BLOCKS 3128        // 391 q-chunks * 8 (bid%8: 0-3 -> half0, 4-7 -> half1)
#define M_BLOCKS 3125        // 50000/16

typedef __attribute__((ext_vector_type(8))) _Float16 half8;
typedef __attribute__((ext_vector_type(4))) float float4v;
typedef __attribute__((ext_vector_type(2))) float float2v;

// pack: src (u16) | w (fp16) << 16
__device__ __forceinline__ int pack_edge(int s, float w) {
    return (int)(((unsigned)__half_as_ushort(__float2half(w)) << 16) | (unsigned)(s & 0xFFFF));
}

// decode 8 fp8 (e4m3) packed in uint2 -> 8 floats
__device__ __forceinline__ void fp8x8_to_f32(uint2 v, float* f) {
    float2v a = __builtin_amdgcn_cvt_pk_f32_fp8(v.x, false);
    float2v b = __builtin_amdgcn_cvt_pk_f32_fp8(v.x, true);
    float2v c = __builtin_amdgcn_cvt_pk_f32_fp8(v.y, false);
    float2v d = __builtin_amdgcn_cvt_pk_f32_fp8(v.y, true);
    f[0] = a[0]; f[1] = a[1]; f[2] = b[0]; f[3] = b[1];
    f[4] = c[0]; f[5] = c[1]; f[6] = d[0]; f[7] = d[1];
}

// encode 8 floats -> 8 fp8 in uint2
__device__ __forceinline__ uint2 f32x8_to_fp8(const float* f) {
    unsigned lo = 0, hi = 0;
    lo = __builtin_amdgcn_cvt_pk_fp8_f32(f[0], f[1], lo, false);
    lo = __builtin_amdgcn_cvt_pk_fp8_f32(f[2], f[3], lo, true);
    hi = __builtin_amdgcn_cvt_pk_fp8_f32(f[4], f[5], hi, false);
    hi = __builtin_amdgcn_cvt_pk_fp8_f32(f[6], f[7], hi, true);
    return make_uint2(lo, hi);
}

__device__ __forceinline__ void bucket_one(int d, int s, float wv, int g,
                                           int* __restrict__ cnt,
                                           int* __restrict__ edge_buf) {
    if ((d & 7) == g) {
        int pos = atomicAdd(&cnt[d], 1);
        edge_buf[(size_t)d * SLOT + pos] = pack_edge(s, wv);
    }
}

// ---------------- fused prep: bucket + wt_prep + init, ONE dispatch --------
// r7 lesson: bucket is pinned at ~44us regardless of bytes (latency floor of
// 800K scattered atomic+store pairs). wt + fp8 init run in the same dispatch
// inside bucket's latency shadow. cnt zeroed by hipMemsetAsync beforehand.
__global__ __launch_bounds__(256) void prep_kernel(const int* __restrict__ src,
                                                   const int* __restrict__ dst,
                                                   const float* __restrict__ w,
                                                   int* __restrict__ cnt,
                                                   int* __restrict__ edge_buf,
                                                   const float* __restrict__ W,
                                                   __half* __restrict__ Wt,
                                                   const float4* __restrict__ x,
                                                   uint2* __restrict__ xh0) {
    int bid = blockIdx.x;
    int tid = threadIdx.x;
    if (bid < BUCKET_BLOCKS) {
        int g     = bid & 7;
        int chunk = bid >> 3;
        int base  = (chunk * 256 + tid) * EPB;
        if (base >= N_EDGES) return;
        int4   d4a = *(const int4*)(dst + base);
        int4   d4b = *(const int4*)(dst + base + 4);
        int4   s4a = *(const int4*)(src + base);
        int4   s4b = *(const int4*)(src + base + 4);
        float4 w4a = *(const float4*)(w + base);
        float4 w4b = *(const float4*)(w + base + 4);
        bucket_one(d4a.x, s4a.x, w4a.x, g, cnt, edge_buf);
        bucket_one(d4a.y, s4a.y, w4a.y, g, cnt, edge_buf);
        bucket_one(d4a.z, s4a.z, w4a.z, g, cnt, edge_buf);
        bucket_one(d4a.w, s4a.w, w4a.w, g, cnt, edge_buf);
        bucket_one(d4b.x, s4b.x, w4b.x, g, cnt, edge_buf);
        bucket_one(d4b.y, s4b.y, w4b.y, g, cnt, edge_buf);
        bucket_one(d4b.z, s4b.z, w4b.z, g, cnt, edge_buf);
        bucket_one(d4b.w, s4b.w, w4b.w, g, cnt, edge_buf);
    } else if (bid < BUCKET_BLOCKS + WT_BLOCKS) {
        int i = (bid - BUCKET_BLOCKS) * 256 + tid;   // < 65536 exact
        int l   = i >> 14;
        int rem = i & 16383;
        int k = rem >> 7;
        int n = rem & 127;
        Wt[(size_t)l * DIM * DIM + n * DIM + k] =
            __float2half(W[(size_t)l * DIM * DIM + k * DIM + n]);
    } else {
        int i = (bid - BUCKET_BLOCKS - WT_BLOCKS) * 256 + tid;  // < 800000 exact
        float4 a = x[(size_t)i * 2];
        float4 b = x[(size_t)i * 2 + 1];
        float f[8] = { a.x, a.y, a.z, a.w, b.x, b.y, b.z, b.w };
        xh0[i] = f32x8_to_fp8(f);
    }
}

// Process 8 edges for this lane's node, HALF-row granularity: 8-lane subgroup
// covers 64B (8 uint2) of each gathered row. m holds meta for slots
// base..base+7 (lane sgb+u holds slot base+u). Dead slots exec-masked off.
__device__ __forceinline__ void batch8h(const uint2* __restrict__ x8,
                                        int m, int base, int cnt_r, int sgb, int hc,
                                        float* accf, float& wsum) {
    uint2 v[8]; float wv[8];
    #pragma unroll
    for (int u = 0; u < 8; ++u) {
        int p = __shfl(m, sgb | u, 64);
        bool live = (base + u) < cnt_r;
        wv[u] = live
                  ? __half2float(__ushort_as_half((unsigned short)((unsigned)p >> 16)))
                  : 0.f;
        uint2 vv = make_uint2(0u, 0u);
        if (live) vv = x8[(size_t)(p & 0xFFFF) * 16 + hc];
        v[u] = vv;
    }
    #pragma unroll
    for (int u = 0; u < 8; ++u) {
        wsum += wv[u];
        float f[8];
        fp8x8_to_f32(v[u], f);
        #pragma unroll
        for (int t = 0; t < 8; ++t)
            accf[t] += wv[u] * f[t];
    }
}

// ---------------- gather: A = segsum(w * xin[src]), HALF-DIM partitioned ----
// Rows are 128B = 2 cache lines; half-rows are line-disjoint, so each half's
// working set is 3.2MB -- FITS a 4MiB per-XCD L2 (full fp8 X = 6.4MB doesn't,
// which is why r5-r8 gathers ran at ~2.5TB/s: L2 thrash, L3/HBM latency).
// bid%8 in [0,4) -> half 0, [4,8) -> half 1: with the empirical bid%8->XCD
// round-robin, each XCD touches only ONE half -> L2-resident gather.
// Wave = 8 nodes x 8 lanes; per-lane code identical shape to old batch8.
// No LDS, no barriers. A staged fp16 [N][128]; wsum fp32 (written by half0).
__global__ __launch_bounds__(256) void gather_kernel(const uint2* __restrict__ xin8,
                                                     const int* __restrict__ cnt_arr,
                                                     const int* __restrict__ edge_buf,
                                                     __half* __restrict__ A,
                                                     float* __restrict__ wsumg) {
    int q = blockIdx.x >> 3, rr = blockIdx.x & 7;
    int half = rr >> 2;
    int tile = q * 4 + (rr & 3);
    if (tile >= GTILES) return;
    int tid  = threadIdx.x;
    int wave = tid >> 6;
    int lane = tid & 63;
    int sg  = lane >> 3;      // node subgroup 0..7
    int c   = lane & 7;       // 8B chunk within half-row
    int sgb = lane & 0x38;
    int node_r = tile * 32 + wave * 8 + sg;
    bool valid = node_r < N_NODES;
    size_t mb = (size_t)(valid ? node_r : 0) * SLOT;
    // upfront: slots 0-31 meta (live for ~99% of waves' trip decisions);
    // slots 32-47 deferred into the rare branch.
    int m0a = edge_buf[mb + c];
    int m0b = edge_buf[mb + 8 + c];
    int m1a = edge_buf[mb + 16 + c];
    int m1b = edge_buf[mb + 24 + c];
    int cnt_r = valid ? cnt_arr[node_r] : 0;
    int maxc = cnt_r;
    maxc = max(maxc, __shfl_xor(maxc, 8, 64));
    maxc = max(maxc, __shfl_xor(maxc, 16, 64));
    maxc = max(maxc, __shfl_xor(maxc, 32, 64));   // wave-uniform

    int hc = half * 8 + c;    // uint2 offset within full row
    float accf[8];
    #pragma unroll
    for (int t = 0; t < 8; ++t) accf[t] = 0.f;
    float wsum = 0.f;

    batch8h(xin8, m0a, 0, cnt_r, sgb, hc, accf, wsum);
    batch8h(xin8, m0b, 8, cnt_r, sgb, hc, accf, wsum);
    if (maxc > 16) {
        batch8h(xin8, m1a, 16, cnt_r, sgb, hc, accf, wsum);
        batch8h(xin8, m1b, 24, cnt_r, sgb, hc, accf, wsum);
    }
    if (maxc > 32) {
        int m2a = edge_buf[mb + 32 + c];
        int m2b = edge_buf[mb + 40 + c];
        batch8h(xin8, m2a, 32, cnt_r, sgb, hc, accf, wsum);
        batch8h(xin8, m2b, 40, cnt_r, sgb, hc, accf, wsum);
    }

    if (valid) {
        union { __half2 hh[4]; float4 f4; } ua;
        ua.hh[0] = __floats2half2_rn(accf[0], accf[1]);
        ua.hh[1] = __floats2half2_rn(accf[2], accf[3]);
        ua.hh[2] = __floats2half2_rn(accf[4], accf[5]);
        ua.hh[3] = __floats2half2_rn(accf[6], accf[7]);
        *(float4*)(A + (size_t)node_r * DIM + half * 64 + c * 8) = ua.f4;
        if (half == 0 && c == 0) wsumg[node_r] = wsum;
    }
}

// ---------------- mm: A @ W + wsum*b -> relu -> fp8 xout / FINAL combine ----
// Pure BW-bound consumer of the A staging buffer (~20MB). Same MFMA tile as
// the old fused layer. NOTE: plain __launch_bounds__(256) (r4 spill lesson).
#define AP 136
template <bool FINAL>
__global__ __launch_bounds__(256) void mm_kernel(const __half* __restrict__ A,
                                                 const float* __restrict__ wsumg,
                                                 const __half* __restrict__ Wt,
                                                 const float* __restrict__ bl,
                                                 uint2* __restrict__ xout,
                                                 float* __restrict__ hidden,
                                                 const float* __restrict__ temp,
                                                 const uint2* __restrict__ x0h,
                                                 const uint2* __restrict__ x1h,
                                                 const uint2* __restrict__ x2h,
                                                 const uint2* __restrict__ x3h) {
    __shared__ __half Ah[16][AP];
    __shared__ float winS[16];
    int tid  = threadIdx.x;
    int wave = tid >> 6;
    int lane = tid & 63;
    int gnode0 = blockIdx.x * 16;

    {
        int row = tid >> 4, ch = tid & 15;
        *(float4*)&Ah[row][ch * 8] =
            *(const float4*)(A + (size_t)(gnode0 + row) * DIM + ch * 8);
    }
    if (tid < 16) winS[tid] = wsumg[gnode0 + tid];
    __syncthreads();

    // MFMA: wave computes rows 0..15 x cols [wave*32, wave*32+32)
    int am  = lane & 15;
    int ak8 = (lane >> 4) * 8;
    float4v acc0 = (float4v)(0.f), acc1 = (float4v)(0.f);
    #pragma unroll
    for (int kk = 0; kk < 4; ++kk) {
        int k0 = kk * 32 + ak8;
        half8 a  = *(const half8*)&Ah[am][k0];
        half8 b0 = *(const half8*)(Wt + (size_t)(wave * 32 + am) * DIM + k0);
        half8 b1 = *(const half8*)(Wt + (size_t)(wave * 32 + 16 + am) * DIM + k0);
        acc0 = __builtin_amdgcn_mfma_f32_16x16x32_f16(a, b0, acc0, 0, 0, 0);
        acc1 = __builtin_amdgcn_mfma_f32_16x16x32_f16(a, b1, acc1, 0, 0, 0);
    }
    __syncthreads();

    // epilogue: + wsum*b, relu, back to LDS fp16 for coalesced stores
    int q  = lane >> 4;
    int cc = lane & 15;
    {
        int col = wave * 32 + cc;
        float bv = bl[col];
        #pragma unroll
        for (int j = 0; j < 4; ++j) {
            int row = q * 4 + j;
            Ah[row][col] = __float2half(fmaxf(acc0[j] + winS[row] * bv, 0.f));
        }
        col = wave * 32 + 16 + cc;
        bv = bl[col];
        #pragma unroll
        for (int j = 0; j < 4; ++j) {
            int row = q * 4 + j;
            Ah[row][col] = __float2half(fmaxf(acc1[j] + winS[row] * bv, 0.f));
        }
    }
    __syncthreads();

    // 256 threads == 16 rows x 16 chunks
    int row = tid >> 4;
    int ch  = tid & 15;
    int gnode = gnode0 + row;
    half8 hv = *(const half8*)&Ah[row][ch * 8];
    size_t ro = (size_t)gnode * 16 + ch;

    if constexpr (!FINAL) {
        float f[8];
        #pragma unroll
        for (int t = 0; t < 8; ++t) f[t] = (float)hv[t];
        xout[ro] = f32x8_to_fp8(f);
    } else {
        float t0 = temp[0], t1 = temp[1], t2 = temp[2], t3 = temp[3], t4 = temp[4];
        uint2 u0 = x0h[ro], u1 = x1h[ro], u2 = x2h[ro], u3 = x3h[ro];
        float f0[8], f1[8], f2[8], f3[8];
        fp8x8_to_f32(u0, f0);
        fp8x8_to_f32(u1, f1);
        fp8x8_to_f32(u2, f2);
        fp8x8_to_f32(u3, f3);
        float out[8];
        #pragma unroll
        for (int t = 0; t < 8; ++t)
            out[t] = t0 * f0[t] + t1 * f1[t] + t2 * f2[t]
                   + t3 * f3[t] + t4 * (float)hv[t];
        size_t o = (size_t)gnode * DIM + ch * 8;
        *(float4*)(hidden + o)     = make_float4(out[0], out[1], out[2], out[3]);
        *(float4*)(hidden + o + 4) = make_float4(out[4], out[5], out[6], out[7]);
    }
}

extern "C" void kernel_launch(void* const* d_in, const int* in_sizes, int n_in,
                              void* d_out, int out_size, void* d_ws, size_t ws_size,
                              hipStream_t stream) {
    const float* x    = (const float*)d_in[0];
    const float* w    = (const float*)d_in[1];
    const int*   src  = (const int*)d_in[2];
    const int*   dst  = (const int*)d_in[3];
    const float* W    = (const float*)d_in[4];
    const float* b    = (const float*)d_in[5];
    const float* temp = (const float*)d_in[6];
    float* hidden = (float*)d_out;

    char* ws = (char*)d_ws;
    uint2* X0 = (uint2*)ws;                  ws += (size_t)N_NODES * DIM;   // fp8: 1B/elem
    uint2* X1 = (uint2*)ws;                  ws += (size_t)N_NODES * DIM;
    uint2* X2 = (uint2*)ws;                  ws += (size_t)N_NODES * DIM;
    uint2* X3 = (uint2*)ws;                  ws += (size_t)N_NODES * DIM;
    __half* Wt = (__half*)ws;                ws += (size_t)LAYERS * DIM * DIM * sizeof(__half);
    int* cnt = (int*)ws;                     ws += (size_t)N_NODES * sizeof(int);
    int* edge_buf = (int*)ws;                ws += (size_t)(N_NODES * SLOT + 64) * sizeof(int);
    __half* A = (__half*)ws;                 ws += (size_t)N_NODES * DIM * sizeof(__half);
    float* wsumg = (float*)ws;               ws += (size_t)N_NODES * sizeof(float);

    hipMemsetAsync(cnt, 0, (size_t)N_NODES * sizeof(int), stream);
    prep_kernel<<<BUCKET_BLOCKS + WT_BLOCKS + INIT_BLOCKS, 256, 0, stream>>>(
        src, dst, w, cnt, edge_buf, W, Wt, (const float4*)x, X0);

    uint2* Xs[4] = { X0, X1, X2, X3 };
    for (int l = 0; l < LAYERS; ++l) {
        gather_kernel<<<G_BLOCKS, 256, 0, stream>>>(
            Xs[l], cnt, edge_buf, A, wsumg);
        if (l < LAYERS - 1) {
            mm_kernel<false><<<M_BLOCKS, 256, 0, stream>>>(
                A, wsumg, Wt + (size_t)l * DIM * DIM, b + (size_t)l * DIM,
                Xs[l + 1], hidden, temp, nullptr, nullptr, nullptr, nullptr);
        } else {
            mm_kernel<true><<<M_BLOCKS, 256, 0, stream>>>(
                A, wsumg, Wt + (size_t)l * DIM * DIM, b + (size_t)l * DIM,
                nullptr, hidden, temp, X0, X1, X2, X3);
        }
    }
}

// Round 10
// 244.617 us; speedup vs baseline: 1.1747x; 1.1747x over previous
//
#include <hip/hip_runtime.h>
#include <hip/hip_fp16.h>

#define N_NODES 50000
#define N_EDGES 800000
#define DIM 128
#define LAYERS 4
#define SLOT 48           // padded slots per node; 4B/slot -> node region = 192B = 3 lines
#define EPB 8             // edges scanned per thread in bucket (N_EDGES % EPB == 0)
#define CNT_STRIDE 6250   // nodes per XCD class (50000/8); cnt permuted by d&7

#define BUCKET_BLOCKS 3128   // ceil(800000/(256*8)) * 8 = 391*8
#define WT_BLOCKS 256        // LAYERS*DIM*DIM/256
#define INIT_BLOCKS 3125     // N_NODES*DIM/8/256 (8 elems -> 8 fp8 bytes per thread)

typedef __attribute__((ext_vector_type(8))) _Float16 half8;
typedef __attribute__((ext_vector_type(4))) float float4v;
typedef __attribute__((ext_vector_type(2))) float float2v;

// pack: src (u16) | w (fp16) << 16
__device__ __forceinline__ int pack_edge(int s, float w) {
    return (int)(((unsigned)__half_as_ushort(__float2half(w)) << 16) | (unsigned)(s & 0xFFFF));
}

// decode 8 fp8 (e4m3) packed in uint2 -> 8 floats
__device__ __forceinline__ void fp8x8_to_f32(uint2 v, float* f) {
    float2v a = __builtin_amdgcn_cvt_pk_f32_fp8(v.x, false);
    float2v b = __builtin_amdgcn_cvt_pk_f32_fp8(v.x, true);
    float2v c = __builtin_amdgcn_cvt_pk_f32_fp8(v.y, false);
    float2v d = __builtin_amdgcn_cvt_pk_f32_fp8(v.y, true);
    f[0] = a[0]; f[1] = a[1]; f[2] = b[0]; f[3] = b[1];
    f[4] = c[0]; f[5] = c[1]; f[6] = d[0]; f[7] = d[1];
}

// encode 8 floats -> 8 fp8 in uint2
__device__ __forceinline__ uint2 f32x8_to_fp8(const float* f) {
    unsigned lo = 0, hi = 0;
    lo = __builtin_amdgcn_cvt_pk_fp8_f32(f[0], f[1], lo, false);
    lo = __builtin_amdgcn_cvt_pk_fp8_f32(f[2], f[3], lo, true);
    hi = __builtin_amdgcn_cvt_pk_fp8_f32(f[4], f[5], hi, false);
    hi = __builtin_amdgcn_cvt_pk_fp8_f32(f[6], f[7], hi, true);
    return make_uint2(lo, hi);
}

// cnt is PERMUTED: counter for node d lives at (d&7)*CNT_STRIDE + (d>>3).
// Rationale (r9): linear cnt puts all 8 d&7 classes in every 64B line, so
// all 8 XCDs atomically update the same lines -> cross-XCD ownership
// ping-pong on every atomic. Permuted, each XCD's counters are exclusive
// contiguous lines -> atomics stay XCD-L2-local.
__device__ __forceinline__ void bucket_one(int d, int s, float wv, int g,
                                           int* __restrict__ cnt,
                                           int* __restrict__ edge_buf) {
    if ((d & 7) == g) {
        int pos = atomicAdd(&cnt[g * CNT_STRIDE + (d >> 3)], 1);
        edge_buf[(size_t)d * SLOT + pos] = pack_edge(s, wv);
    }
}

// ---------------- fused prep: bucket + wt_prep + init, ONE dispatch --------
// r7 lesson: bucket is pinned at a latency floor regardless of bytes. wt +
// fp8 init run in the same dispatch inside bucket's latency shadow.
// cnt zeroed by hipMemsetAsync beforehand.
__global__ __launch_bounds__(256) void prep_kernel(const int* __restrict__ src,
                                                   const int* __restrict__ dst,
                                                   const float* __restrict__ w,
                                                   int* __restrict__ cnt,
                                                   int* __restrict__ edge_buf,
                                                   const float* __restrict__ W,
                                                   __half* __restrict__ Wt,
                                                   const float4* __restrict__ x,
                                                   uint2* __restrict__ xh0) {
    int bid = blockIdx.x;
    int tid = threadIdx.x;
    if (bid < BUCKET_BLOCKS) {
        int g     = bid & 7;
        int chunk = bid >> 3;
        int base  = (chunk * 256 + tid) * EPB;
        if (base >= N_EDGES) return;
        int4   d4a = *(const int4*)(dst + base);
        int4   d4b = *(const int4*)(dst + base + 4);
        int4   s4a = *(const int4*)(src + base);
        int4   s4b = *(const int4*)(src + base + 4);
        float4 w4a = *(const float4*)(w + base);
        float4 w4b = *(const float4*)(w + base + 4);
        bucket_one(d4a.x, s4a.x, w4a.x, g, cnt, edge_buf);
        bucket_one(d4a.y, s4a.y, w4a.y, g, cnt, edge_buf);
        bucket_one(d4a.z, s4a.z, w4a.z, g, cnt, edge_buf);
        bucket_one(d4a.w, s4a.w, w4a.w, g, cnt, edge_buf);
        bucket_one(d4b.x, s4b.x, w4b.x, g, cnt, edge_buf);
        bucket_one(d4b.y, s4b.y, w4b.y, g, cnt, edge_buf);
        bucket_one(d4b.z, s4b.z, w4b.z, g, cnt, edge_buf);
        bucket_one(d4b.w, s4b.w, w4b.w, g, cnt, edge_buf);
    } else if (bid < BUCKET_BLOCKS + WT_BLOCKS) {
        int i = (bid - BUCKET_BLOCKS) * 256 + tid;   // < 65536 exact
        int l   = i >> 14;
        int rem = i & 16383;
        int k = rem >> 7;
        int n = rem & 127;
        Wt[(size_t)l * DIM * DIM + n * DIM + k] =
            __float2half(W[(size_t)l * DIM * DIM + k * DIM + n]);
    } else {
        int i = (bid - BUCKET_BLOCKS - WT_BLOCKS) * 256 + tid;  // < 800000 exact
        float4 a = x[(size_t)i * 2];
        float4 b = x[(size_t)i * 2 + 1];
        float f[8] = { a.x, a.y, a.z, a.w, b.x, b.y, b.z, b.w };
        xh0[i] = f32x8_to_fp8(f);
    }
}

// Process 8 edges (slots base..base+7, meta register m) for this lane's node.
// batch8 (NOT 16: r7 showed the wider window costs VGPR 72->~104, waves
// 7->4/SIMD, and regressed ~13us). Dead slots: load exec-masked off.
__device__ __forceinline__ void batch8(const uint2* __restrict__ x8,
                                       int m, int base, int cnt_r, int r, int c,
                                       float* accf, float& wsum) {
    uint2 v[8]; float wv[8];
    #pragma unroll
    for (int u = 0; u < 8; ++u) {
        int jj = base + u;
        int p  = __shfl(m, (r << 4) | (jj & 15), 64);
        bool live = (jj < cnt_r);
        wv[u] = live
                  ? __half2float(__ushort_as_half((unsigned short)((unsigned)p >> 16)))
                  : 0.f;
        uint2 vv = make_uint2(0u, 0u);
        if (live) vv = x8[(size_t)(p & 0xFFFF) * 16 + c];
        v[u] = vv;
    }
    #pragma unroll
    for (int u = 0; u < 8; ++u) {
        wsum += wv[u];
        float f[8];
        fp8x8_to_f32(v[u], f);
        #pragma unroll
        for (int t = 0; t < 8; ++t)
            accf[t] += wv[u] * f[t];
    }
}

// Fused layer: gather A = segsum(w * xin[src]) -> 16x128 fp16 tile in LDS ->
// MFMA A@W + win*b -> relu. (r9's gather/mm split with half-dim L2
// partitioning REGRESSED -- gather is scatter-latency-bound, not
// L2-capacity-bound; staging traffic was pure cost. Fused form kept.)
// FINAL=false: store layer output as fp8 to xout. NO hidden traffic.
// FINAL=true : full GPR combine, all-fp8 inputs:
//   hidden = t0*X0 + t1*X1 + t2*X2 + t3*X3 + t4*out   (xin == X3)
// NOTE: plain __launch_bounds__(256). r4's (256,6) forced VGPR 68->40,
// spilled batch8 arrays (WRITE 12.5->218MB, 2.3x slower). Never cap.
#define AP 136
template <bool FINAL>
__global__ __launch_bounds__(256) void layer_kernel(const uint2* __restrict__ xin8,
                                                    const int* __restrict__ cnt_arr,
                                                    const int* __restrict__ edge_buf,
                                                    const __half* __restrict__ Wt,
                                                    const float* __restrict__ bl,
                                                    uint2* __restrict__ xout,
                                                    float* __restrict__ hidden,
                                                    const float* __restrict__ temp,
                                                    const uint2* __restrict__ x0h,
                                                    const uint2* __restrict__ x1h,
                                                    const uint2* __restrict__ x2h) {
    __shared__ __half Ah[16][AP];
    __shared__ float winS[16];
    int tid  = threadIdx.x;
    int wave = tid >> 6;
    int lane = tid & 63;
    int r = lane >> 4;    // node subgroup 0..3
    int c = lane & 15;    // 8B chunk within fp8 row
    int node0  = blockIdx.x * 16 + wave * 4;
    int node_r = node0 + r;

    // upfront, independent: m0/m1 meta (slots 0-31) + permuted cnt (broadcast
    // per 16-lane group). m2 (slots 32-47) deferred into the rare branch.
    size_t mb = (size_t)node_r * SLOT;
    int m0 = edge_buf[mb + c];
    int m1 = edge_buf[mb + 16 + c];
    int cnt_r = cnt_arr[(node_r & 7) * CNT_STRIDE + (node_r >> 3)];

    int maxc = cnt_r;
    maxc = max(maxc, __shfl_xor(maxc, 16, 64));
    maxc = max(maxc, __shfl_xor(maxc, 32, 64));   // wave-uniform

    float accf[8];
    #pragma unroll
    for (int t = 0; t < 8; ++t) accf[t] = 0.f;
    float wsum = 0.f;

    batch8(xin8, m0, 0, cnt_r, r, c, accf, wsum);
    batch8(xin8, m0, 8, cnt_r, r, c, accf, wsum);
    if (maxc > 16) {
        batch8(xin8, m1, 16, cnt_r, r, c, accf, wsum);
        batch8(xin8, m1, 24, cnt_r, r, c, accf, wsum);
    }
    if (maxc > 32) {
        int m2 = edge_buf[mb + 32 + c];
        batch8(xin8, m2, 32, cnt_r, r, c, accf, wsum);
        batch8(xin8, m2, 40, cnt_r, r, c, accf, wsum);
    }

    // A tile (fp32 acc -> fp16) into LDS; 16 rows x 128 cols
    union { __half2 hh[4]; float4 f4; } ua;
    ua.hh[0] = __floats2half2_rn(accf[0], accf[1]);
    ua.hh[1] = __floats2half2_rn(accf[2], accf[3]);
    ua.hh[2] = __floats2half2_rn(accf[4], accf[5]);
    ua.hh[3] = __floats2half2_rn(accf[6], accf[7]);
    int lr = wave * 4 + r;
    *(float4*)&Ah[lr][c * 8] = ua.f4;
    if (c == 0) winS[lr] = wsum;
    __syncthreads();

    // MFMA tail: wave computes rows 0..15 x cols [wave*32, wave*32+32)
    int am  = lane & 15;
    int ak8 = (lane >> 4) * 8;
    float4v acc0 = (float4v)(0.f), acc1 = (float4v)(0.f);
    #pragma unroll
    for (int kk = 0; kk < 4; ++kk) {
        int k0 = kk * 32 + ak8;
        half8 a  = *(const half8*)&Ah[am][k0];
        half8 b0 = *(const half8*)(Wt + (size_t)(wave * 32 + am) * DIM + k0);
        half8 b1 = *(const half8*)(Wt + (size_t)(wave * 32 + 16 + am) * DIM + k0);
        acc0 = __builtin_amdgcn_mfma_f32_16x16x32_f16(a, b0, acc0, 0, 0, 0);
        acc1 = __builtin_amdgcn_mfma_f32_16x16x32_f16(a, b1, acc1, 0, 0, 0);
    }
    __syncthreads();

    // epilogue: + win*b, relu, back to LDS fp16 for coalesced stores
    int q  = lane >> 4;
    int cc = lane & 15;
    {
        int col = wave * 32 + cc;
        float bv = bl[col];
        #pragma unroll
        for (int j = 0; j < 4; ++j) {
            int row = q * 4 + j;
            Ah[row][col] = __float2half(fmaxf(acc0[j] + winS[row] * bv, 0.f));
        }
        col = wave * 32 + 16 + cc;
        bv = bl[col];
        #pragma unroll
        for (int j = 0; j < 4; ++j) {
            int row = q * 4 + j;
            Ah[row][col] = __float2half(fmaxf(acc1[j] + winS[row] * bv, 0.f));
        }
    }
    __syncthreads();

    // 256 threads == 16 rows x 16 chunks
    int row = tid >> 4;
    int ch  = tid & 15;
    int gnode = blockIdx.x * 16 + row;
    half8 hv = *(const half8*)&Ah[row][ch * 8];
    size_t ro = (size_t)gnode * 16 + ch;

    if constexpr (!FINAL) {
        float f[8];
        #pragma unroll
        for (int t = 0; t < 8; ++t) f[t] = (float)hv[t];
        xout[ro] = f32x8_to_fp8(f);
    } else {
        float t0 = temp[0], t1 = temp[1], t2 = temp[2], t3 = temp[3], t4 = temp[4];
        uint2 u0 = x0h[ro], u1 = x1h[ro], u2 = x2h[ro], u3 = xin8[ro];
        float f0[8], f1[8], f2[8], f3[8];
        fp8x8_to_f32(u0, f0);
        fp8x8_to_f32(u1, f1);
        fp8x8_to_f32(u2, f2);
        fp8x8_to_f32(u3, f3);
        float out[8];
        #pragma unroll
        for (int t = 0; t < 8; ++t)
            out[t] = t0 * f0[t] + t1 * f1[t] + t2 * f2[t]
                   + t3 * f3[t] + t4 * (float)hv[t];
        size_t o = (size_t)gnode * DIM + ch * 8;
        *(float4*)(hidden + o)     = make_float4(out[0], out[1], out[2], out[3]);
        *(float4*)(hidden + o + 4) = make_float4(out[4], out[5], out[6], out[7]);
    }
}

extern "C" void kernel_launch(void* const* d_in, const int* in_sizes, int n_in,
                              void* d_out, int out_size, void* d_ws, size_t ws_size,
                              hipStream_t stream) {
    const float* x    = (const float*)d_in[0];
    const float* w    = (const float*)d_in[1];
    const int*   src  = (const int*)d_in[2];
    const int*   dst  = (const int*)d_in[3];
    const float* W    = (const float*)d_in[4];
    const float* b    = (const float*)d_in[5];
    const float* temp = (const float*)d_in[6];
    float* hidden = (float*)d_out;

    char* ws = (char*)d_ws;
    // 4 fp8 x buffers: init->X0, L1 X0->X1, L2 X1->X2, L3 X2->X3,
    // L4 gathers X3 and combines X0..X3 + its own output into hidden.
    uint2* X0 = (uint2*)ws;                  ws += (size_t)N_NODES * DIM;   // fp8: 1B/elem
    uint2* X1 = (uint2*)ws;                  ws += (size_t)N_NODES * DIM;
    uint2* X2 = (uint2*)ws;                  ws += (size_t)N_NODES * DIM;
    uint2* X3 = (uint2*)ws;                  ws += (size_t)N_NODES * DIM;
    __half* Wt = (__half*)ws;                ws += (size_t)LAYERS * DIM * DIM * sizeof(__half);
    int* cnt = (int*)ws;                     ws += (size_t)N_NODES * sizeof(int);
    int* edge_buf = (int*)ws;                ws += (size_t)(N_NODES * SLOT + 64) * sizeof(int);

    hipMemsetAsync(cnt, 0, (size_t)N_NODES * sizeof(int), stream);
    prep_kernel<<<BUCKET_BLOCKS + WT_BLOCKS + INIT_BLOCKS, 256, 0, stream>>>(
        src, dst, w, cnt, edge_buf, W, Wt, (const float4*)x, X0);

    const int layer_blocks = N_NODES / 16;   // 3125, exact
    layer_kernel<false><<<layer_blocks, 256, 0, stream>>>(
        X0, cnt, edge_buf, Wt + 0 * DIM * DIM, b + 0 * DIM,
        X1, hidden, temp, nullptr, nullptr, nullptr);
    layer_kernel<false><<<layer_blocks, 256, 0, stream>>>(
        X1, cnt, edge_buf, Wt + 1 * DIM * DIM, b + 1 * DIM,
        X2, hidden, temp, nullptr, nullptr, nullptr);
    layer_kernel<false><<<layer_blocks, 256, 0, stream>>>(
        X2, cnt, edge_buf, Wt + 2 * DIM * DIM, b + 2 * DIM,
        X3, hidden, temp, nullptr, nullptr, nullptr);
    layer_kernel<true><<<layer_blocks, 256, 0, stream>>>(
        X3, cnt, edge_buf, Wt + 3 * DIM * DIM, b + 3 * DIM,
        nullptr, hidden, temp, X0, X1, X2);
}